// Round 1
// baseline (6335.588 us; speedup 1.0000x reference)
//
#include <hip/hip_runtime.h>

// Problem constants (from reference)
#define N_C 50000
#define N_V 100000
#define N_A 5000
#define E_C2V 1600000
#define E_A2V 1000000
#define D_V 13
#define D_C 14
#define D_A 14
#define EMB 32

// h[j] += v * Wrow[j] for j in [0,32). Wrow is wave-uniform -> SMEM-eligible.
__device__ __forceinline__ void accrow(float* __restrict__ h, float v,
                                       const float* __restrict__ Wrow) {
#pragma unroll
  for (int j = 0; j < EMB; ++j) h[j] = fmaf(v, Wrow[j], h[j]);
}

// -------- edge MLP (FIN=28): in = [x_t(13), x_s(14), ea(1)], scatter by tgt
__global__ __launch_bounds__(256) void k_edge_gh(
    int nE,
    const int* __restrict__ src, const int* __restrict__ tgt,
    const float* __restrict__ x_t,   // 13-dim (variable nodes)
    const float* __restrict__ x_s,   // 14-dim (cut / aggregate nodes)
    const float* __restrict__ ea,    // 1 per edge
    const float* __restrict__ W1, const float* __restrict__ b1,
    const float* __restrict__ W2, const float* __restrict__ b2,
    float* __restrict__ aggr, float* __restrict__ cnt) {
  int e = blockIdx.x * blockDim.x + threadIdx.x;
  if (e >= nE) return;
  int s = src[e];
  int t = tgt[e];
  float h[EMB];
#pragma unroll
  for (int j = 0; j < EMB; ++j) h[j] = b1[j];
  const float* pt = x_t + (size_t)t * D_V;
#pragma unroll
  for (int i = 0; i < D_V; ++i) accrow(h, pt[i], W1 + i * EMB);
  const float* ps = x_s + (size_t)s * D_C;
#pragma unroll
  for (int i = 0; i < D_C; ++i) accrow(h, ps[i], W1 + (D_V + i) * EMB);
  accrow(h, ea[e], W1 + 27 * EMB);
#pragma unroll
  for (int j = 0; j < EMB; ++j) h[j] = fmaxf(h[j], 0.0f);
  float o[EMB];
#pragma unroll
  for (int j = 0; j < EMB; ++j) o[j] = b2[j];
#pragma unroll
  for (int k = 0; k < EMB; ++k) accrow(o, h[k], W2 + k * EMB);
  float* dst = aggr + (size_t)t * EMB;
#pragma unroll
  for (int j = 0; j < EMB; ++j) atomicAdd(dst + j, fmaxf(o[j], 0.0f));
  atomicAdd(cnt + t, 1.0f);
}

// -------- g_a edge MLP (FIN=47): in = [x_a(14), f_v(32), ea(1)], scatter by src
__global__ __launch_bounds__(256) void k_edge_ga(
    int nE,
    const int* __restrict__ src, const int* __restrict__ tgt,
    const float* __restrict__ xa,    // 14-dim
    const float* __restrict__ fv,    // 32-dim
    const float* __restrict__ ea,
    const float* __restrict__ W1, const float* __restrict__ b1,
    const float* __restrict__ W2, const float* __restrict__ b2,
    float* __restrict__ aggr, float* __restrict__ cnt) {
  int e = blockIdx.x * blockDim.x + threadIdx.x;
  if (e >= nE) return;
  int s = src[e];
  int t = tgt[e];
  float h[EMB];
#pragma unroll
  for (int j = 0; j < EMB; ++j) h[j] = b1[j];
  const float* ps = xa + (size_t)s * D_A;
#pragma unroll
  for (int i = 0; i < D_A; ++i) accrow(h, ps[i], W1 + i * EMB);
  const float* pf = fv + (size_t)t * EMB;
#pragma unroll
  for (int i = 0; i < EMB; ++i) accrow(h, pf[i], W1 + (D_A + i) * EMB);
  accrow(h, ea[e], W1 + 46 * EMB);
#pragma unroll
  for (int j = 0; j < EMB; ++j) h[j] = fmaxf(h[j], 0.0f);
  float o[EMB];
#pragma unroll
  for (int j = 0; j < EMB; ++j) o[j] = b2[j];
#pragma unroll
  for (int k = 0; k < EMB; ++k) accrow(o, h[k], W2 + k * EMB);
  float* dst = aggr + (size_t)s * EMB;
#pragma unroll
  for (int j = 0; j < EMB; ++j) atomicAdd(dst + j, fmaxf(o[j], 0.0f));
  atomicAdd(cnt + s, 1.0f);
}

// -------- f_v node MLP (FIN=77): in = [x_v(13), aggr_g/cnt(32), aggr_h/cnt(32)]
__global__ __launch_bounds__(256) void k_node_fv(
    const float* __restrict__ xv,
    const float* __restrict__ aggr_g, const float* __restrict__ cnt_g,
    const float* __restrict__ aggr_h, const float* __restrict__ cnt_h,
    const float* __restrict__ W1, const float* __restrict__ b1,
    const float* __restrict__ W2, const float* __restrict__ b2,
    float* __restrict__ fv_out) {
  int v = blockIdx.x * blockDim.x + threadIdx.x;
  if (v >= N_V) return;
  float h[EMB];
#pragma unroll
  for (int j = 0; j < EMB; ++j) h[j] = b1[j];
  const float* pv = xv + (size_t)v * D_V;
#pragma unroll
  for (int i = 0; i < D_V; ++i) accrow(h, pv[i], W1 + i * EMB);
  float ig = 1.0f / fmaxf(cnt_g[v], 1.0f);
  const float* pg = aggr_g + (size_t)v * EMB;
#pragma unroll
  for (int i = 0; i < EMB; ++i) accrow(h, pg[i] * ig, W1 + (D_V + i) * EMB);
  float ih = 1.0f / fmaxf(cnt_h[v], 1.0f);
  const float* ph = aggr_h + (size_t)v * EMB;
#pragma unroll
  for (int i = 0; i < EMB; ++i) accrow(h, ph[i] * ih, W1 + (D_V + EMB + i) * EMB);
#pragma unroll
  for (int j = 0; j < EMB; ++j) h[j] = fmaxf(h[j], 0.0f);
  float o[EMB];
#pragma unroll
  for (int j = 0; j < EMB; ++j) o[j] = b2[j];
#pragma unroll
  for (int k = 0; k < EMB; ++k) accrow(o, h[k], W2 + k * EMB);
  float* dst = fv_out + (size_t)v * EMB;
#pragma unroll
  for (int j = 0; j < EMB; ++j) dst[j] = fmaxf(o[j], 0.0f);
}

// -------- f_a node MLP (FIN=46): in = [x_a(14), aggr_a/cnt(32)] -> d_out
__global__ __launch_bounds__(256) void k_node_fa(
    const float* __restrict__ xa,
    const float* __restrict__ aggr_a, const float* __restrict__ cnt_a,
    const float* __restrict__ W1, const float* __restrict__ b1,
    const float* __restrict__ W2, const float* __restrict__ b2,
    float* __restrict__ out) {
  int a = blockIdx.x * blockDim.x + threadIdx.x;
  if (a >= N_A) return;
  float h[EMB];
#pragma unroll
  for (int j = 0; j < EMB; ++j) h[j] = b1[j];
  const float* pa = xa + (size_t)a * D_A;
#pragma unroll
  for (int i = 0; i < D_A; ++i) accrow(h, pa[i], W1 + i * EMB);
  float ia = 1.0f / fmaxf(cnt_a[a], 1.0f);
  const float* pg = aggr_a + (size_t)a * EMB;
#pragma unroll
  for (int i = 0; i < EMB; ++i) accrow(h, pg[i] * ia, W1 + (D_A + i) * EMB);
#pragma unroll
  for (int j = 0; j < EMB; ++j) h[j] = fmaxf(h[j], 0.0f);
  float o[EMB];
#pragma unroll
  for (int j = 0; j < EMB; ++j) o[j] = b2[j];
#pragma unroll
  for (int k = 0; k < EMB; ++k) accrow(o, h[k], W2 + k * EMB);
  float* dst = out + (size_t)a * EMB;
#pragma unroll
  for (int j = 0; j < EMB; ++j) dst[j] = fmaxf(o[j], 0.0f);
}

extern "C" void kernel_launch(void* const* d_in, const int* in_sizes, int n_in,
                              void* d_out, int out_size, void* d_ws, size_t ws_size,
                              hipStream_t stream) {
  const float* x_c = (const float*)d_in[0];
  const float* x_v = (const float*)d_in[1];
  const float* x_a = (const float*)d_in[2];
  const int* c2v_s = (const int*)d_in[3];
  const int* c2v_t = (const int*)d_in[4];
  const int* a2v_s = (const int*)d_in[5];
  const int* a2v_t = (const int*)d_in[6];
  const float* ea_c2v = (const float*)d_in[7];
  const float* ea_a2v = (const float*)d_in[8];
  const float* gv_W1 = (const float*)d_in[9];
  const float* gv_b1 = (const float*)d_in[10];
  const float* gv_W2 = (const float*)d_in[11];
  const float* gv_b2 = (const float*)d_in[12];
  const float* hv_W1 = (const float*)d_in[13];
  const float* hv_b1 = (const float*)d_in[14];
  const float* hv_W2 = (const float*)d_in[15];
  const float* hv_b2 = (const float*)d_in[16];
  const float* fv_W1 = (const float*)d_in[17];
  const float* fv_b1 = (const float*)d_in[18];
  const float* fv_W2 = (const float*)d_in[19];
  const float* fv_b2 = (const float*)d_in[20];
  const float* ga_W1 = (const float*)d_in[21];
  const float* ga_b1 = (const float*)d_in[22];
  const float* ga_W2 = (const float*)d_in[23];
  const float* ga_b2 = (const float*)d_in[24];
  const float* fa_W1 = (const float*)d_in[25];
  const float* fa_b1 = (const float*)d_in[26];
  const float* fa_W2 = (const float*)d_in[27];
  const float* fa_b2 = (const float*)d_in[28];

  // workspace layout (floats)
  float* ws = (float*)d_ws;
  float* aggr_g = ws;                                  // N_V*32
  float* aggr_h = aggr_g + (size_t)N_V * EMB;          // N_V*32
  float* aggr_a = aggr_h + (size_t)N_V * EMB;          // N_A*32
  float* cnt_g = aggr_a + (size_t)N_A * EMB;           // N_V
  float* cnt_h = cnt_g + N_V;                          // N_V
  float* cnt_a = cnt_h + N_V;                          // N_A
  float* fv = cnt_a + N_A;                             // N_V*32

  size_t zero_floats =
      (size_t)N_V * EMB * 2 + (size_t)N_A * EMB + (size_t)N_V * 2 + N_A;
  hipMemsetAsync(d_ws, 0, zero_floats * sizeof(float), stream);

  k_edge_gh<<<(E_C2V + 255) / 256, 256, 0, stream>>>(
      E_C2V, c2v_s, c2v_t, x_v, x_c, ea_c2v, gv_W1, gv_b1, gv_W2, gv_b2,
      aggr_g, cnt_g);
  k_edge_gh<<<(E_A2V + 255) / 256, 256, 0, stream>>>(
      E_A2V, a2v_s, a2v_t, x_v, x_a, ea_a2v, hv_W1, hv_b1, hv_W2, hv_b2,
      aggr_h, cnt_h);
  k_node_fv<<<(N_V + 255) / 256, 256, 0, stream>>>(
      x_v, aggr_g, cnt_g, aggr_h, cnt_h, fv_W1, fv_b1, fv_W2, fv_b2, fv);
  k_edge_ga<<<(E_A2V + 255) / 256, 256, 0, stream>>>(
      E_A2V, a2v_s, a2v_t, x_a, fv, ea_a2v, ga_W1, ga_b1, ga_W2, ga_b2,
      aggr_a, cnt_a);
  k_node_fa<<<(N_A + 255) / 256, 256, 0, stream>>>(
      x_a, aggr_a, cnt_a, fa_W1, fa_b1, fa_W2, fa_b2, (float*)d_out);
}

// Round 3
// 4862.666 us; speedup vs baseline: 1.3029x; 1.3029x over previous
//
#include <hip/hip_runtime.h>

// Problem constants (from reference)
#define N_C 50000
#define N_V 100000
#define N_A 5000
#define E_C2V 1600000
#define E_A2V 1000000
#define D_V 13
#define D_C 14
#define D_A 14
#define EMB 32

// h[j] += v * Wrow[j] for j in [0,32). Wrow is wave-uniform -> scalar path.
__device__ __forceinline__ void accrow(float* __restrict__ h, float v,
                                       const float* __restrict__ Wrow) {
#pragma unroll
  for (int j = 0; j < EMB; ++j) h[j] = fmaf(v, Wrow[j], h[j]);
}

// -------- degree histogram
__global__ __launch_bounds__(256) void k_count(const int* __restrict__ idx,
                                               int* __restrict__ deg, int n) {
  int e = blockIdx.x * blockDim.x + threadIdx.x;
  if (e < n) atomicAdd(&deg[idx[e]], 1);
}

// -------- slot allocation: off[i] = disjoint range of size deg[i]
__global__ __launch_bounds__(256) void k_alloc(const int* __restrict__ deg,
                                               int* __restrict__ off,
                                               int* __restrict__ head,
                                               int* __restrict__ ctr, int n) {
  int i = blockIdx.x * blockDim.x + threadIdx.x;
  int lane = threadIdx.x & 63;
  int d = (i < n) ? deg[i] : 0;
  int v = d;  // inclusive wave scan
#pragma unroll
  for (int s = 1; s < 64; s <<= 1) {
    int t = __shfl_up(v, s, 64);
    if (lane >= s) v += t;
  }
  int total = __shfl(v, 63, 64);
  int base = 0;
  if (lane == 63) base = atomicAdd(ctr, total);
  base = __shfl(base, 63, 64);
  if (i < n) {
    int o = base + v - d;
    off[i] = o;
    head[i] = o;
  }
}

// -------- CSR fill: perm[slot] = edge id, grouped by idx[e]
__global__ __launch_bounds__(256) void k_fill(const int* __restrict__ idx,
                                              int* __restrict__ head,
                                              int* __restrict__ perm, int n) {
  int e = blockIdx.x * blockDim.x + threadIdx.x;
  if (e < n) {
    int pos = atomicAdd(&head[idx[e]], 1);
    perm[pos] = e;
  }
}

// one edge of the FIN=28 edge MLP (shared shape for g_v and h_v):
// in = [xv(13), xs_row(14), ea(1)]; sum[j] += relu(out_j)
__device__ __forceinline__ void edge_contrib28(
    float* __restrict__ sum, const float* __restrict__ xv,
    const float* __restrict__ xs_row, float ea_e,
    const float* __restrict__ W1, const float* __restrict__ b1,
    const float* __restrict__ W2, const float* __restrict__ b2) {
  float h[EMB];
#pragma unroll
  for (int j = 0; j < EMB; ++j) h[j] = b1[j];
#pragma unroll
  for (int i = 0; i < D_V; ++i) accrow(h, xv[i], W1 + i * EMB);
#pragma unroll
  for (int i = 0; i < D_C; ++i) accrow(h, xs_row[i], W1 + (D_V + i) * EMB);
  accrow(h, ea_e, W1 + 27 * EMB);
#pragma unroll
  for (int j = 0; j < EMB; ++j) h[j] = fmaxf(h[j], 0.0f);
#pragma unroll
  for (int j = 0; j < EMB; ++j) {
    float o = b2[j];
#pragma unroll
    for (int k = 0; k < EMB; ++k) o = fmaf(h[k], W2[k * EMB + j], o);
    sum[j] += fmaxf(o, 0.0f);
  }
}

// -------- fused v-node update: thread per node.
// mean over g_v(c2v edges) + mean over h_v(a2v edges) + f_v MLP -> fv_out
__global__ __launch_bounds__(256) void k_fused_v(
    const int* __restrict__ c2v_s, const int* __restrict__ a2v_s,
    const int* __restrict__ perm_g, const int* __restrict__ off_g,
    const int* __restrict__ deg_g,
    const int* __restrict__ perm_h, const int* __restrict__ off_h,
    const int* __restrict__ deg_h,
    const float* __restrict__ xv_g, const float* __restrict__ xc,
    const float* __restrict__ xa,
    const float* __restrict__ ea_g, const float* __restrict__ ea_h,
    const float* __restrict__ gW1, const float* __restrict__ gb1,
    const float* __restrict__ gW2, const float* __restrict__ gb2,
    const float* __restrict__ hW1, const float* __restrict__ hb1,
    const float* __restrict__ hW2, const float* __restrict__ hb2,
    const float* __restrict__ fW1, const float* __restrict__ fb1,
    const float* __restrict__ fW2, const float* __restrict__ fb2,
    float* __restrict__ fv_out) {
  int v = blockIdx.x * blockDim.x + threadIdx.x;
  if (v >= N_V) return;
  float xv[D_V];
#pragma unroll
  for (int i = 0; i < D_V; ++i) xv[i] = xv_g[(size_t)v * D_V + i];

  float sum[EMB];
#pragma unroll
  for (int j = 0; j < EMB; ++j) sum[j] = 0.0f;
  int dg = deg_g[v], og = off_g[v];
  for (int r = 0; r < dg; ++r) {
    int e = perm_g[og + r];
    int s = c2v_s[e];
    edge_contrib28(sum, xv, xc + (size_t)s * D_C, ea_g[e], gW1, gb1, gW2, gb2);
  }
  float invg = 1.0f / fmaxf((float)dg, 1.0f);

  // f_v hidden, seeded with xv part + mean_g part
  float hf[EMB];
#pragma unroll
  for (int j = 0; j < EMB; ++j) hf[j] = fb1[j];
#pragma unroll
  for (int i = 0; i < D_V; ++i) accrow(hf, xv[i], fW1 + i * EMB);
#pragma unroll
  for (int i = 0; i < EMB; ++i) accrow(hf, sum[i] * invg, fW1 + (D_V + i) * EMB);

  // h side (reuse sum)
#pragma unroll
  for (int j = 0; j < EMB; ++j) sum[j] = 0.0f;
  int dh = deg_h[v], oh = off_h[v];
  for (int r = 0; r < dh; ++r) {
    int e = perm_h[oh + r];
    int s = a2v_s[e];
    edge_contrib28(sum, xv, xa + (size_t)s * D_A, ea_h[e], hW1, hb1, hW2, hb2);
  }
  float invh = 1.0f / fmaxf((float)dh, 1.0f);
#pragma unroll
  for (int i = 0; i < EMB; ++i)
    accrow(hf, sum[i] * invh, fW1 + (D_V + EMB + i) * EMB);

#pragma unroll
  for (int j = 0; j < EMB; ++j) hf[j] = fmaxf(hf[j], 0.0f);
  float* dst = fv_out + (size_t)v * EMB;
#pragma unroll
  for (int j = 0; j < EMB; ++j) {
    float o = fb2[j];
#pragma unroll
    for (int k = 0; k < EMB; ++k) o = fmaf(hf[k], fW2[k * EMB + j], o);
    dst[j] = fmaxf(o, 0.0f);  // relu_out=True (second relu is idempotent)
  }
}

// -------- g_a aggregation: one wave per a-node. FIN=47: [xa(14), fv(32), ea(1)]
__global__ __launch_bounds__(256) void k_aggr_a(
    const int* __restrict__ a2v_t, const int* __restrict__ perm,
    const int* __restrict__ off, const int* __restrict__ deg,
    const float* __restrict__ xa_g, const float* __restrict__ fv,
    const float* __restrict__ ea,
    const float* __restrict__ W1, const float* __restrict__ b1,
    const float* __restrict__ W2, const float* __restrict__ b2,
    float* __restrict__ ma) {
  int w = (blockIdx.x * blockDim.x + threadIdx.x) >> 6;  // node (wave-uniform)
  int lane = threadIdx.x & 63;
  if (w >= N_A) return;
  float xa[D_A];
#pragma unroll
  for (int i = 0; i < D_A; ++i) xa[i] = xa_g[(size_t)w * D_A + i];
  int d = deg[w], o0 = off[w];
  float sum[EMB];
#pragma unroll
  for (int j = 0; j < EMB; ++j) sum[j] = 0.0f;
  for (int r = lane; r < d; r += 64) {
    int e = perm[o0 + r];  // lanes read consecutive perm entries: coalesced
    int t = a2v_t[e];
    const float* pf = fv + (size_t)t * EMB;
    float h[EMB];
#pragma unroll
    for (int j = 0; j < EMB; ++j) h[j] = b1[j];
#pragma unroll
    for (int i = 0; i < D_A; ++i) accrow(h, xa[i], W1 + i * EMB);
#pragma unroll
    for (int i = 0; i < EMB; ++i) accrow(h, pf[i], W1 + (D_A + i) * EMB);
    accrow(h, ea[e], W1 + 46 * EMB);
#pragma unroll
    for (int j = 0; j < EMB; ++j) h[j] = fmaxf(h[j], 0.0f);
#pragma unroll
    for (int j = 0; j < EMB; ++j) {
      float o = b2[j];
#pragma unroll
      for (int k = 0; k < EMB; ++k) o = fmaf(h[k], W2[k * EMB + j], o);
      sum[j] += fmaxf(o, 0.0f);
    }
  }
  // butterfly reduce the 32-vector across 64 lanes (wave-converged here)
#pragma unroll
  for (int m = 1; m < 64; m <<= 1) {
#pragma unroll
    for (int j = 0; j < EMB; ++j) sum[j] += __shfl_xor(sum[j], m, 64);
  }
  if (lane == 0) {
    float inv = 1.0f / fmaxf((float)d, 1.0f);
    float* dst = ma + (size_t)w * EMB;
#pragma unroll
    for (int j = 0; j < EMB; ++j) dst[j] = sum[j] * inv;
  }
}

// -------- f_a node MLP (FIN=46): in = [x_a(14), ma(32)] -> d_out
__global__ __launch_bounds__(256) void k_node_fa(
    const float* __restrict__ xa, const float* __restrict__ ma,
    const float* __restrict__ W1, const float* __restrict__ b1,
    const float* __restrict__ W2, const float* __restrict__ b2,
    float* __restrict__ out) {
  int a = blockIdx.x * blockDim.x + threadIdx.x;
  if (a >= N_A) return;
  float h[EMB];
#pragma unroll
  for (int j = 0; j < EMB; ++j) h[j] = b1[j];
  const float* pa = xa + (size_t)a * D_A;
#pragma unroll
  for (int i = 0; i < D_A; ++i) accrow(h, pa[i], W1 + i * EMB);
  const float* pg = ma + (size_t)a * EMB;
#pragma unroll
  for (int i = 0; i < EMB; ++i) accrow(h, pg[i], W1 + (D_A + i) * EMB);
#pragma unroll
  for (int j = 0; j < EMB; ++j) h[j] = fmaxf(h[j], 0.0f);
  float* dst = out + (size_t)a * EMB;
#pragma unroll
  for (int j = 0; j < EMB; ++j) {
    float o = b2[j];
#pragma unroll
    for (int k = 0; k < EMB; ++k) o = fmaf(h[k], W2[k * EMB + j], o);
    dst[j] = fmaxf(o, 0.0f);
  }
}

extern "C" void kernel_launch(void* const* d_in, const int* in_sizes, int n_in,
                              void* d_out, int out_size, void* d_ws, size_t ws_size,
                              hipStream_t stream) {
  const float* x_c = (const float*)d_in[0];
  const float* x_v = (const float*)d_in[1];
  const float* x_a = (const float*)d_in[2];
  const int* c2v_s = (const int*)d_in[3];
  const int* c2v_t = (const int*)d_in[4];
  const int* a2v_s = (const int*)d_in[5];
  const int* a2v_t = (const int*)d_in[6];
  const float* ea_c2v = (const float*)d_in[7];
  const float* ea_a2v = (const float*)d_in[8];
  const float* gv_W1 = (const float*)d_in[9];
  const float* gv_b1 = (const float*)d_in[10];
  const float* gv_W2 = (const float*)d_in[11];
  const float* gv_b2 = (const float*)d_in[12];
  const float* hv_W1 = (const float*)d_in[13];
  const float* hv_b1 = (const float*)d_in[14];
  const float* hv_W2 = (const float*)d_in[15];
  const float* hv_b2 = (const float*)d_in[16];
  const float* fv_W1 = (const float*)d_in[17];
  const float* fv_b1 = (const float*)d_in[18];
  const float* fv_W2 = (const float*)d_in[19];
  const float* fv_b2 = (const float*)d_in[20];
  const float* ga_W1 = (const float*)d_in[21];
  const float* ga_b1 = (const float*)d_in[22];
  const float* ga_W2 = (const float*)d_in[23];
  const float* ga_b2 = (const float*)d_in[24];
  const float* fa_W1 = (const float*)d_in[25];
  const float* fa_b1 = (const float*)d_in[26];
  const float* fa_W2 = (const float*)d_in[27];
  const float* fa_b2 = (const float*)d_in[28];

  // ---- workspace layout (total ~30 MB; round-1 proved ~39 MB is safe) ----
  int* ip = (int*)d_ws;
  int* deg_g = ip;                  // 100000  -- memset region start
  int* deg_h = deg_g + N_V;         // 100000
  int* deg_a = deg_h + N_V;         // 5000
  int* ctr = deg_a + N_A;           // 4       -- memset region end (205004)
  int* off_g = ctr + 4;             // 100000
  int* off_h = off_g + N_V;         // 100000
  int* off_a = off_h + N_V;         // 5000
  int* head_g = off_a + N_A;        // 100000
  int* head_h = head_g + N_V;       // 100000
  int* head_a = head_h + N_V;       // 5000
  int* perm_g = head_a + N_A;       // 1600000
  int* perm_h = perm_g + E_C2V;     // 1000000
  int* perm_a = perm_h + E_A2V;     // 1000000
  // float region (int count 4,215,004 -> byte offset divisible by 16)
  float* fp = (float*)(perm_a + E_A2V);
  float* fv = fp;                               // N_V*32
  float* ma = fv + (size_t)N_V * EMB;           // N_A*32

  hipMemsetAsync(d_ws, 0, (size_t)(2 * N_V + N_A + 4) * sizeof(int), stream);

  // degrees
  k_count<<<(E_C2V + 255) / 256, 256, 0, stream>>>(c2v_t, deg_g, E_C2V);
  k_count<<<(E_A2V + 255) / 256, 256, 0, stream>>>(a2v_t, deg_h, E_A2V);
  k_count<<<(E_A2V + 255) / 256, 256, 0, stream>>>(a2v_s, deg_a, E_A2V);
  // slot allocation
  k_alloc<<<(N_V + 255) / 256, 256, 0, stream>>>(deg_g, off_g, head_g, ctr + 0, N_V);
  k_alloc<<<(N_V + 255) / 256, 256, 0, stream>>>(deg_h, off_h, head_h, ctr + 1, N_V);
  k_alloc<<<(N_A + 255) / 256, 256, 0, stream>>>(deg_a, off_a, head_a, ctr + 2, N_A);
  // CSR fill
  k_fill<<<(E_C2V + 255) / 256, 256, 0, stream>>>(c2v_t, head_g, perm_g, E_C2V);
  k_fill<<<(E_A2V + 255) / 256, 256, 0, stream>>>(a2v_t, head_h, perm_h, E_A2V);
  k_fill<<<(E_A2V + 255) / 256, 256, 0, stream>>>(a2v_s, head_a, perm_a, E_A2V);
  // fused v-node update (g_v + h_v means + f_v MLP)
  k_fused_v<<<(N_V + 255) / 256, 256, 0, stream>>>(
      c2v_s, a2v_s, perm_g, off_g, deg_g, perm_h, off_h, deg_h,
      x_v, x_c, x_a, ea_c2v, ea_a2v,
      gv_W1, gv_b1, gv_W2, gv_b2, hv_W1, hv_b1, hv_W2, hv_b2,
      fv_W1, fv_b1, fv_W2, fv_b2, fv);
  // g_a aggregation (wave per a-node)
  k_aggr_a<<<((size_t)N_A * 64 + 255) / 256, 256, 0, stream>>>(
      a2v_t, perm_a, off_a, deg_a, x_a, fv, ea_a2v,
      ga_W1, ga_b1, ga_W2, ga_b2, ma);
  // f_a -> out
  k_node_fa<<<(N_A + 255) / 256, 256, 0, stream>>>(
      x_a, ma, fa_W1, fa_b1, fa_W2, fa_b2, (float*)d_out);
}

// Round 4
// 1813.769 us; speedup vs baseline: 3.4931x; 2.6810x over previous
//
#include <hip/hip_runtime.h>

// Problem constants (from reference)
#define N_C 50000
#define N_V 100000
#define N_A 5000
#define E_C2V 1600000
#define E_A2V 1000000
#define D_V 13
#define D_C 14
#define D_A 14
#define EMB 32

// h[j] += v * Wrow[j] for j in [0,32). Wrow is wave-uniform -> scalar path.
__device__ __forceinline__ void accrow(float* __restrict__ h, float v,
                                       const float* __restrict__ Wrow) {
#pragma unroll
  for (int j = 0; j < EMB; ++j) h[j] = fmaf(v, Wrow[j], h[j]);
}

// -------- degree histogram
__global__ __launch_bounds__(256) void k_count(const int* __restrict__ idx,
                                               int* __restrict__ deg, int n) {
  int e = blockIdx.x * blockDim.x + threadIdx.x;
  if (e < n) atomicAdd(&deg[idx[e]], 1);
}

// -------- slot allocation: off[i] = disjoint range of size deg[i]
__global__ __launch_bounds__(256) void k_alloc(const int* __restrict__ deg,
                                               int* __restrict__ off,
                                               int* __restrict__ head,
                                               int* __restrict__ ctr, int n) {
  int i = blockIdx.x * blockDim.x + threadIdx.x;
  int lane = threadIdx.x & 63;
  int d = (i < n) ? deg[i] : 0;
  int v = d;  // inclusive wave scan
#pragma unroll
  for (int s = 1; s < 64; s <<= 1) {
    int t = __shfl_up(v, s, 64);
    if (lane >= s) v += t;
  }
  int total = __shfl(v, 63, 64);
  int base = 0;
  if (lane == 63) base = atomicAdd(ctr, total);
  base = __shfl(base, 63, 64);
  if (i < n) {
    int o = base + v - d;
    off[i] = o;
    head[i] = o;
  }
}

// -------- CSR fill: perm[slot] = edge id, grouped by idx[e]
__global__ __launch_bounds__(256) void k_fill(const int* __restrict__ idx,
                                              int* __restrict__ head,
                                              int* __restrict__ perm, int n) {
  int e = blockIdx.x * blockDim.x + threadIdx.x;
  if (e < n) {
    int pos = atomicAdd(&head[idx[e]], 1);
    perm[pos] = e;
  }
}

// one edge of the FIN=28 edge MLP (shared shape for g_v and h_v):
// in = [xv(13), xs_row(14), ea(1)]; sum[j] += relu(out_j)
__device__ __forceinline__ void edge_contrib28(
    float* __restrict__ sum, const float* __restrict__ xv,
    const float* __restrict__ xs_row, float ea_e,
    const float* __restrict__ W1, const float* __restrict__ b1,
    const float* __restrict__ W2, const float* __restrict__ b2) {
  float h[EMB];
#pragma unroll
  for (int j = 0; j < EMB; ++j) h[j] = b1[j];
#pragma unroll
  for (int i = 0; i < D_V; ++i) accrow(h, xv[i], W1 + i * EMB);
#pragma unroll
  for (int i = 0; i < D_C; ++i) accrow(h, xs_row[i], W1 + (D_V + i) * EMB);
  accrow(h, ea_e, W1 + 27 * EMB);
#pragma unroll
  for (int j = 0; j < EMB; ++j) h[j] = fmaxf(h[j], 0.0f);
#pragma unroll
  for (int j = 0; j < EMB; ++j) {
    float o = b2[j];
#pragma unroll
    for (int k = 0; k < EMB; ++k) o = fmaf(h[k], W2[k * EMB + j], o);
    sum[j] += fmaxf(o, 0.0f);
  }
}

// -------- fused v-node update: 16 lanes per node (4 nodes per wave).
// Each lane computes full edge MLPs for its stride-16 share of edges;
// 16-lane butterfly reduces the 32-vector sums; then f_v is computed
// channel-parallel (lane j -> channels 2j,2j+1) with hidden exchanged in LDS.
// N_V = 100000 = 6250 blocks * 16 groups exactly (no remainder guard needed).
__global__ __launch_bounds__(256) void k_v(
    const int* __restrict__ c2v_s, const int* __restrict__ a2v_s,
    const int* __restrict__ perm_g, const int* __restrict__ off_g,
    const int* __restrict__ deg_g,
    const int* __restrict__ perm_h, const int* __restrict__ off_h,
    const int* __restrict__ deg_h,
    const float* __restrict__ xv_g, const float* __restrict__ xc,
    const float* __restrict__ xa,
    const float* __restrict__ ea_g, const float* __restrict__ ea_h,
    const float* __restrict__ gW1, const float* __restrict__ gb1,
    const float* __restrict__ gW2, const float* __restrict__ gb2,
    const float* __restrict__ hW1, const float* __restrict__ hb1,
    const float* __restrict__ hW2, const float* __restrict__ hb2,
    const float* __restrict__ fW1, const float* __restrict__ fb1,
    const float* __restrict__ fW2, const float* __restrict__ fb2,
    float* __restrict__ fv_out) {
  __shared__ float hid[16][33];  // +1 pad: groups hit distinct banks
  int gib = threadIdx.x >> 4;    // group (node) within block
  int l = threadIdx.x & 15;      // lane within group
  int v = blockIdx.x * 16 + gib;

  float xv[D_V];
#pragma unroll
  for (int i = 0; i < D_V; ++i) xv[i] = xv_g[(size_t)v * D_V + i];

  // ---- g side (c2v edges into v)
  float sumg[EMB];
#pragma unroll
  for (int j = 0; j < EMB; ++j) sumg[j] = 0.0f;
  int dg = deg_g[v], og = off_g[v];
  for (int r = l; r < dg; r += 16) {
    int e = perm_g[og + r];
    int s = c2v_s[e];
    edge_contrib28(sumg, xv, xc + (size_t)s * D_C, ea_g[e], gW1, gb1, gW2, gb2);
  }
  // ---- h side (a2v edges into v)
  float sumh[EMB];
#pragma unroll
  for (int j = 0; j < EMB; ++j) sumh[j] = 0.0f;
  int dh = deg_h[v], oh = off_h[v];
  for (int r = l; r < dh; r += 16) {
    int e = perm_h[oh + r];
    int s = a2v_s[e];
    edge_contrib28(sumh, xv, xa + (size_t)s * D_A, ea_h[e], hW1, hb1, hW2, hb2);
  }
  // ---- butterfly reduce within the 16-lane group (masks 1,2,4,8)
#pragma unroll
  for (int m = 1; m < 16; m <<= 1) {
#pragma unroll
    for (int j = 0; j < EMB; ++j) {
      sumg[j] += __shfl_xor(sumg[j], m, 64);
      sumh[j] += __shfl_xor(sumh[j], m, 64);
    }
  }
  float invg = 1.0f / fmaxf((float)dg, 1.0f);
  float invh = 1.0f / fmaxf((float)dh, 1.0f);

  // ---- f_v MLP, channel-parallel: lane l computes channels 2l, 2l+1.
  // All lanes hold the full mean vectors in registers after the butterfly.
  int c = 2 * l;
  float h0 = fb1[c], h1 = fb1[c + 1];
#pragma unroll
  for (int i = 0; i < D_V; ++i) {
    float2 w = *(const float2*)(fW1 + i * EMB + c);  // coalesced per group
    h0 = fmaf(xv[i], w.x, h0);
    h1 = fmaf(xv[i], w.y, h1);
  }
#pragma unroll
  for (int i = 0; i < EMB; ++i) {
    float2 w = *(const float2*)(fW1 + (D_V + i) * EMB + c);
    float mi = sumg[i] * invg;
    h0 = fmaf(mi, w.x, h0);
    h1 = fmaf(mi, w.y, h1);
  }
#pragma unroll
  for (int i = 0; i < EMB; ++i) {
    float2 w = *(const float2*)(fW1 + (D_V + EMB + i) * EMB + c);
    float mi = sumh[i] * invh;
    h0 = fmaf(mi, w.x, h0);
    h1 = fmaf(mi, w.y, h1);
  }
  hid[gib][c] = fmaxf(h0, 0.0f);
  hid[gib][c + 1] = fmaxf(h1, 0.0f);
  __syncthreads();
  float o0 = fb2[c], o1 = fb2[c + 1];
#pragma unroll
  for (int k = 0; k < EMB; ++k) {
    float hk = hid[gib][k];  // same-address broadcast within group
    float2 w = *(const float2*)(fW2 + k * EMB + c);
    o0 = fmaf(hk, w.x, o0);
    o1 = fmaf(hk, w.y, o1);
  }
  // relu_out=True, then reference applies relu again (idempotent)
  ((float2*)(fv_out + (size_t)v * EMB))[l] =
      make_float2(fmaxf(o0, 0.0f), fmaxf(o1, 0.0f));
}

// -------- g_a aggregation: one wave per a-node. FIN=47: [xa(14), fv(32), ea(1)]
__global__ __launch_bounds__(256) void k_aggr_a(
    const int* __restrict__ a2v_t, const int* __restrict__ perm,
    const int* __restrict__ off, const int* __restrict__ deg,
    const float* __restrict__ xa_g, const float* __restrict__ fv,
    const float* __restrict__ ea,
    const float* __restrict__ W1, const float* __restrict__ b1,
    const float* __restrict__ W2, const float* __restrict__ b2,
    float* __restrict__ ma) {
  int w = (blockIdx.x * blockDim.x + threadIdx.x) >> 6;  // node (wave-uniform)
  int lane = threadIdx.x & 63;
  if (w >= N_A) return;
  float xa[D_A];
#pragma unroll
  for (int i = 0; i < D_A; ++i) xa[i] = xa_g[(size_t)w * D_A + i];
  int d = deg[w], o0 = off[w];
  float sum[EMB];
#pragma unroll
  for (int j = 0; j < EMB; ++j) sum[j] = 0.0f;
  for (int r = lane; r < d; r += 64) {
    int e = perm[o0 + r];  // lanes read consecutive perm entries: coalesced
    int t = a2v_t[e];
    const float* pf = fv + (size_t)t * EMB;
    float h[EMB];
#pragma unroll
    for (int j = 0; j < EMB; ++j) h[j] = b1[j];
#pragma unroll
    for (int i = 0; i < D_A; ++i) accrow(h, xa[i], W1 + i * EMB);
#pragma unroll
    for (int i = 0; i < EMB; ++i) accrow(h, pf[i], W1 + (D_A + i) * EMB);
    accrow(h, ea[e], W1 + 46 * EMB);
#pragma unroll
    for (int j = 0; j < EMB; ++j) h[j] = fmaxf(h[j], 0.0f);
#pragma unroll
    for (int j = 0; j < EMB; ++j) {
      float o = b2[j];
#pragma unroll
      for (int k = 0; k < EMB; ++k) o = fmaf(h[k], W2[k * EMB + j], o);
      sum[j] += fmaxf(o, 0.0f);
    }
  }
  // butterfly reduce the 32-vector across 64 lanes (wave-converged here)
#pragma unroll
  for (int m = 1; m < 64; m <<= 1) {
#pragma unroll
    for (int j = 0; j < EMB; ++j) sum[j] += __shfl_xor(sum[j], m, 64);
  }
  if (lane == 0) {
    float inv = 1.0f / fmaxf((float)d, 1.0f);
    float* dst = ma + (size_t)w * EMB;
#pragma unroll
    for (int j = 0; j < EMB; ++j) dst[j] = sum[j] * inv;
  }
}

// -------- f_a node MLP (FIN=46): in = [x_a(14), ma(32)] -> d_out
__global__ __launch_bounds__(256) void k_node_fa(
    const float* __restrict__ xa, const float* __restrict__ ma,
    const float* __restrict__ W1, const float* __restrict__ b1,
    const float* __restrict__ W2, const float* __restrict__ b2,
    float* __restrict__ out) {
  int a = blockIdx.x * blockDim.x + threadIdx.x;
  if (a >= N_A) return;
  float h[EMB];
#pragma unroll
  for (int j = 0; j < EMB; ++j) h[j] = b1[j];
  const float* pa = xa + (size_t)a * D_A;
#pragma unroll
  for (int i = 0; i < D_A; ++i) accrow(h, pa[i], W1 + i * EMB);
  const float* pg = ma + (size_t)a * EMB;
#pragma unroll
  for (int i = 0; i < EMB; ++i) accrow(h, pg[i], W1 + (D_A + i) * EMB);
#pragma unroll
  for (int j = 0; j < EMB; ++j) h[j] = fmaxf(h[j], 0.0f);
  float* dst = out + (size_t)a * EMB;
#pragma unroll
  for (int j = 0; j < EMB; ++j) {
    float o = b2[j];
#pragma unroll
    for (int k = 0; k < EMB; ++k) o = fmaf(h[k], W2[k * EMB + j], o);
    dst[j] = fmaxf(o, 0.0f);
  }
}

extern "C" void kernel_launch(void* const* d_in, const int* in_sizes, int n_in,
                              void* d_out, int out_size, void* d_ws, size_t ws_size,
                              hipStream_t stream) {
  const float* x_c = (const float*)d_in[0];
  const float* x_v = (const float*)d_in[1];
  const float* x_a = (const float*)d_in[2];
  const int* c2v_s = (const int*)d_in[3];
  const int* c2v_t = (const int*)d_in[4];
  const int* a2v_s = (const int*)d_in[5];
  const int* a2v_t = (const int*)d_in[6];
  const float* ea_c2v = (const float*)d_in[7];
  const float* ea_a2v = (const float*)d_in[8];
  const float* gv_W1 = (const float*)d_in[9];
  const float* gv_b1 = (const float*)d_in[10];
  const float* gv_W2 = (const float*)d_in[11];
  const float* gv_b2 = (const float*)d_in[12];
  const float* hv_W1 = (const float*)d_in[13];
  const float* hv_b1 = (const float*)d_in[14];
  const float* hv_W2 = (const float*)d_in[15];
  const float* hv_b2 = (const float*)d_in[16];
  const float* fv_W1 = (const float*)d_in[17];
  const float* fv_b1 = (const float*)d_in[18];
  const float* fv_W2 = (const float*)d_in[19];
  const float* fv_b2 = (const float*)d_in[20];
  const float* ga_W1 = (const float*)d_in[21];
  const float* ga_b1 = (const float*)d_in[22];
  const float* ga_W2 = (const float*)d_in[23];
  const float* ga_b2 = (const float*)d_in[24];
  const float* fa_W1 = (const float*)d_in[25];
  const float* fa_b1 = (const float*)d_in[26];
  const float* fa_W2 = (const float*)d_in[27];
  const float* fa_b2 = (const float*)d_in[28];

  // ---- workspace layout (total ~30 MB; proven-safe envelope) ----
  int* ip = (int*)d_ws;
  int* deg_g = ip;                  // 100000  -- memset region start
  int* deg_h = deg_g + N_V;         // 100000
  int* deg_a = deg_h + N_V;         // 5000
  int* ctr = deg_a + N_A;           // 4       -- memset region end (205004)
  int* off_g = ctr + 4;             // 100000
  int* off_h = off_g + N_V;         // 100000
  int* off_a = off_h + N_V;         // 5000
  int* head_g = off_a + N_A;        // 100000
  int* head_h = head_g + N_V;       // 100000
  int* head_a = head_h + N_V;       // 5000
  int* perm_g = head_a + N_A;       // 1600000
  int* perm_h = perm_g + E_C2V;     // 1000000
  int* perm_a = perm_h + E_A2V;     // 1000000
  // float region (int count 4,215,004 -> byte offset divisible by 16)
  float* fp = (float*)(perm_a + E_A2V);
  float* fv = fp;                               // N_V*32
  float* ma = fv + (size_t)N_V * EMB;           // N_A*32

  hipMemsetAsync(d_ws, 0, (size_t)(2 * N_V + N_A + 4) * sizeof(int), stream);

  // degrees
  k_count<<<(E_C2V + 255) / 256, 256, 0, stream>>>(c2v_t, deg_g, E_C2V);
  k_count<<<(E_A2V + 255) / 256, 256, 0, stream>>>(a2v_t, deg_h, E_A2V);
  k_count<<<(E_A2V + 255) / 256, 256, 0, stream>>>(a2v_s, deg_a, E_A2V);
  // slot allocation
  k_alloc<<<(N_V + 255) / 256, 256, 0, stream>>>(deg_g, off_g, head_g, ctr + 0, N_V);
  k_alloc<<<(N_V + 255) / 256, 256, 0, stream>>>(deg_h, off_h, head_h, ctr + 1, N_V);
  k_alloc<<<(N_A + 255) / 256, 256, 0, stream>>>(deg_a, off_a, head_a, ctr + 2, N_A);
  // CSR fill
  k_fill<<<(E_C2V + 255) / 256, 256, 0, stream>>>(c2v_t, head_g, perm_g, E_C2V);
  k_fill<<<(E_A2V + 255) / 256, 256, 0, stream>>>(a2v_t, head_h, perm_h, E_A2V);
  k_fill<<<(E_A2V + 255) / 256, 256, 0, stream>>>(a2v_s, head_a, perm_a, E_A2V);
  // fused v-node update: 16 lanes/node, 6250 blocks (exact fit)
  k_v<<<N_V / 16, 256, 0, stream>>>(
      c2v_s, a2v_s, perm_g, off_g, deg_g, perm_h, off_h, deg_h,
      x_v, x_c, x_a, ea_c2v, ea_a2v,
      gv_W1, gv_b1, gv_W2, gv_b2, hv_W1, hv_b1, hv_W2, hv_b2,
      fv_W1, fv_b1, fv_W2, fv_b2, fv);
  // g_a aggregation (wave per a-node)
  k_aggr_a<<<((size_t)N_A * 64 + 255) / 256, 256, 0, stream>>>(
      a2v_t, perm_a, off_a, deg_a, x_a, fv, ea_a2v,
      ga_W1, ga_b1, ga_W2, ga_b2, ma);
  // f_a -> out
  k_node_fa<<<(N_A + 255) / 256, 256, 0, stream>>>(
      x_a, ma, fa_W1, fa_b1, fa_W2, fa_b2, (float*)d_out);
}

// Round 5
// 1048.946 us; speedup vs baseline: 6.0400x; 1.7291x over previous
//
#include <hip/hip_runtime.h>

// Problem constants (from reference)
#define N_C 50000
#define N_V 100000
#define N_A 5000
#define E_C2V 1600000
#define E_A2V 1000000
#define D_V 13
#define D_C 14
#define D_A 14
#define EMB 32

// h[j] += v * Wrow[j]; Wrow wave-uniform -> scalar loads.
__device__ __forceinline__ void accrow(float* __restrict__ h, float v,
                                       const float* __restrict__ Wrow) {
#pragma unroll
  for (int j = 0; j < EMB; ++j) h[j] = fmaf(v, Wrow[j], h[j]);
}

// -------- degree histogram
__global__ __launch_bounds__(256) void k_count(const int* __restrict__ idx,
                                               int* __restrict__ deg, int n) {
  int e = blockIdx.x * blockDim.x + threadIdx.x;
  if (e < n) atomicAdd(&deg[idx[e]], 1);
}

// -------- slot allocation: off[i] = disjoint range of size deg[i]
__global__ __launch_bounds__(256) void k_alloc(const int* __restrict__ deg,
                                               int* __restrict__ off,
                                               int* __restrict__ head,
                                               int* __restrict__ ctr, int n) {
  int i = blockIdx.x * blockDim.x + threadIdx.x;
  int lane = threadIdx.x & 63;
  int d = (i < n) ? deg[i] : 0;
  int v = d;  // inclusive wave scan
#pragma unroll
  for (int s = 1; s < 64; s <<= 1) {
    int t = __shfl_up(v, s, 64);
    if (lane >= s) v += t;
  }
  int total = __shfl(v, 63, 64);
  int base = 0;
  if (lane == 63) base = atomicAdd(ctr, total);
  base = __shfl(base, 63, 64);
  if (i < n) {
    int o = base + v - d;
    off[i] = o;
    head[i] = o;
  }
}

// -------- CSR fill (perm only, a-side)
__global__ __launch_bounds__(256) void k_fill(const int* __restrict__ idx,
                                              int* __restrict__ head,
                                              int* __restrict__ perm, int n) {
  int e = blockIdx.x * blockDim.x + threadIdx.x;
  if (e < n) {
    int pos = atomicAdd(&head[idx[e]], 1);
    perm[pos] = e;
  }
}

// -------- CSR fill with node-id array (g/h sides)
__global__ __launch_bounds__(256) void k_fill2(const int* __restrict__ idx,
                                               int* __restrict__ head,
                                               int* __restrict__ perm,
                                               int* __restrict__ nidv, int n) {
  int e = blockIdx.x * blockDim.x + threadIdx.x;
  if (e < n) {
    int t = idx[e];
    int pos = atomicAdd(&head[t], 1);
    perm[pos] = e;
    nidv[pos] = t;
  }
}

// -------- edge-parallel v-side edge MLP (FIN=28) + per-wave segmented
// reduction + mean-scale + projection through the f_v W1 slice -> hacc.
// lane = CSR slot (edges sorted by dest v). E % 64 == 0 for both edge sets,
// so every resident wave's 64 slots are valid (excess waves exit whole).
// Per 64-edge chunk: 64 MLPs fully lane-parallel -> LDS [64][33]; then 32
// channel-lanes scan, flush each node-segment: scale by 1/deg, project
// (32x32), atomicAdd into the shared f_v-hidden accumulator hacc.
__global__ __launch_bounds__(256) void k_edge_v(
    int E,
    const int* __restrict__ perm, const int* __restrict__ nid,
    const int* __restrict__ srcv,
    const float* __restrict__ x_t,   // variable-node feats (13)
    const float* __restrict__ x_s,   // source feats (14)
    const float* __restrict__ ea,    // 1 per edge
    const float* __restrict__ W1, const float* __restrict__ b1,
    const float* __restrict__ W2, const float* __restrict__ b2,
    const float* __restrict__ Wp,    // fW1 + (13 or 45)*32: projection slice
    const int* __restrict__ deg,
    float* __restrict__ hacc) {
  __shared__ float vals[4][64][33];  // +1 pad: scan reads conflict-free
  __shared__ int nidl[4][64];
  __shared__ float segx[4][32];
  int wv = threadIdx.x >> 6;
  int lane = threadIdx.x & 63;
  int slot = blockIdx.x * 256 + threadIdx.x;
  if ((slot & ~63) >= E) return;  // wave-uniform exit; no barriers used

  int e = perm[slot];
  int t = nid[slot];
  float eav = ea[e];
  int s = srcv[e];
  const float* xt = x_t + (size_t)t * D_V;
  const float* xs = x_s + (size_t)s * D_C;

  float h[EMB];
#pragma unroll
  for (int j = 0; j < EMB; ++j) h[j] = b1[j];
#pragma unroll
  for (int i = 0; i < D_V; ++i) accrow(h, xt[i], W1 + i * EMB);
#pragma unroll
  for (int i = 0; i < D_C; ++i) accrow(h, xs[i], W1 + (D_V + i) * EMB);
  accrow(h, eav, W1 + 27 * EMB);
#pragma unroll
  for (int j = 0; j < EMB; ++j) h[j] = fmaxf(h[j], 0.0f);
  // second layer, one output channel at a time (W2 index wave-uniform)
#pragma unroll
  for (int j = 0; j < EMB; ++j) {
    float o = b2[j];
#pragma unroll
    for (int k = 0; k < EMB; ++k) o = fmaf(h[k], W2[k * EMB + j], o);
    vals[wv][lane][j] = fmaxf(o, 0.0f);
  }
  nidl[wv][lane] = t;
  // wave-synchronous from here (DS ops in-order within a wave)
  if (lane < EMB) {
    int j = lane;
    float acc = 0.0f;
    for (int r = 0; r < 64; ++r) {
      acc += vals[wv][r][j];
      int cur = nidl[wv][r];
      bool flush = (r == 63) || (nidl[wv][r + 1] != cur);
      if (flush) {  // wave-uniform branch (same for all 32 lanes)
        float inv = 1.0f / fmaxf((float)deg[cur], 1.0f);
        segx[wv][j] = acc * inv;
        float out = 0.0f;
#pragma unroll
        for (int k = 0; k < EMB; ++k)
          out = fmaf(segx[wv][k], Wp[k * EMB + j], out);
        atomicAdd(&hacc[(size_t)cur * EMB + j], out);
        acc = 0.0f;
      }
    }
  }
}

// -------- f_v node MLP on pre-accumulated hidden: thread per node.
// h = relu(fb1 + fW1[0:13]*xv + hacc[v]); fv = relu(fW2*h + fb2)
__global__ __launch_bounds__(256) void k_node_fv(
    const float* __restrict__ xv_g, const float* __restrict__ hacc,
    const float* __restrict__ fW1, const float* __restrict__ fb1,
    const float* __restrict__ fW2, const float* __restrict__ fb2,
    float* __restrict__ fv_out) {
  int v = blockIdx.x * blockDim.x + threadIdx.x;
  if (v >= N_V) return;
  const float* hr = hacc + (size_t)v * EMB;
  float h[EMB];
#pragma unroll
  for (int j = 0; j < EMB; ++j) h[j] = fb1[j] + hr[j];
  const float* pv = xv_g + (size_t)v * D_V;
#pragma unroll
  for (int i = 0; i < D_V; ++i) accrow(h, pv[i], fW1 + i * EMB);
#pragma unroll
  for (int j = 0; j < EMB; ++j) h[j] = fmaxf(h[j], 0.0f);
  float* dst = fv_out + (size_t)v * EMB;
#pragma unroll
  for (int j = 0; j < EMB; ++j) {
    float o = fb2[j];
#pragma unroll
    for (int k = 0; k < EMB; ++k) o = fmaf(h[k], fW2[k * EMB + j], o);
    dst[j] = fmaxf(o, 0.0f);  // relu_out + reference's extra relu (idempotent)
  }
}

// -------- g_a aggregation: one wave per a-node. FIN=47: [xa(14), fv(32), ea(1)]
__global__ __launch_bounds__(256) void k_aggr_a(
    const int* __restrict__ a2v_t, const int* __restrict__ perm,
    const int* __restrict__ off, const int* __restrict__ deg,
    const float* __restrict__ xa_g, const float* __restrict__ fv,
    const float* __restrict__ ea,
    const float* __restrict__ W1, const float* __restrict__ b1,
    const float* __restrict__ W2, const float* __restrict__ b2,
    float* __restrict__ ma) {
  int w = (blockIdx.x * blockDim.x + threadIdx.x) >> 6;  // node (wave-uniform)
  int lane = threadIdx.x & 63;
  if (w >= N_A) return;
  float xa[D_A];
#pragma unroll
  for (int i = 0; i < D_A; ++i) xa[i] = xa_g[(size_t)w * D_A + i];
  int d = deg[w], o0 = off[w];
  float sum[EMB];
#pragma unroll
  for (int j = 0; j < EMB; ++j) sum[j] = 0.0f;
  for (int r = lane; r < d; r += 64) {
    int e = perm[o0 + r];  // coalesced
    int t = a2v_t[e];
    const float* pf = fv + (size_t)t * EMB;
    float h[EMB];
#pragma unroll
    for (int j = 0; j < EMB; ++j) h[j] = b1[j];
#pragma unroll
    for (int i = 0; i < D_A; ++i) accrow(h, xa[i], W1 + i * EMB);
#pragma unroll
    for (int i = 0; i < EMB; ++i) accrow(h, pf[i], W1 + (D_A + i) * EMB);
    accrow(h, ea[e], W1 + 46 * EMB);
#pragma unroll
    for (int j = 0; j < EMB; ++j) h[j] = fmaxf(h[j], 0.0f);
#pragma unroll
    for (int j = 0; j < EMB; ++j) {
      float o = b2[j];
#pragma unroll
      for (int k = 0; k < EMB; ++k) o = fmaf(h[k], W2[k * EMB + j], o);
      sum[j] += fmaxf(o, 0.0f);
    }
  }
#pragma unroll
  for (int m = 1; m < 64; m <<= 1) {
#pragma unroll
    for (int j = 0; j < EMB; ++j) sum[j] += __shfl_xor(sum[j], m, 64);
  }
  if (lane == 0) {
    float inv = 1.0f / fmaxf((float)d, 1.0f);
    float* dst = ma + (size_t)w * EMB;
#pragma unroll
    for (int j = 0; j < EMB; ++j) dst[j] = sum[j] * inv;
  }
}

// -------- f_a node MLP (FIN=46): in = [x_a(14), ma(32)] -> d_out
__global__ __launch_bounds__(256) void k_node_fa(
    const float* __restrict__ xa, const float* __restrict__ ma,
    const float* __restrict__ W1, const float* __restrict__ b1,
    const float* __restrict__ W2, const float* __restrict__ b2,
    float* __restrict__ out) {
  int a = blockIdx.x * blockDim.x + threadIdx.x;
  if (a >= N_A) return;
  float h[EMB];
#pragma unroll
  for (int j = 0; j < EMB; ++j) h[j] = b1[j];
  const float* pa = xa + (size_t)a * D_A;
#pragma unroll
  for (int i = 0; i < D_A; ++i) accrow(h, pa[i], W1 + i * EMB);
  const float* pg = ma + (size_t)a * EMB;
#pragma unroll
  for (int i = 0; i < EMB; ++i) accrow(h, pg[i], W1 + (D_A + i) * EMB);
#pragma unroll
  for (int j = 0; j < EMB; ++j) h[j] = fmaxf(h[j], 0.0f);
  float* dst = out + (size_t)a * EMB;
#pragma unroll
  for (int j = 0; j < EMB; ++j) {
    float o = b2[j];
#pragma unroll
    for (int k = 0; k < EMB; ++k) o = fmaf(h[k], W2[k * EMB + j], o);
    dst[j] = fmaxf(o, 0.0f);
  }
}

extern "C" void kernel_launch(void* const* d_in, const int* in_sizes, int n_in,
                              void* d_out, int out_size, void* d_ws, size_t ws_size,
                              hipStream_t stream) {
  const float* x_c = (const float*)d_in[0];
  const float* x_v = (const float*)d_in[1];
  const float* x_a = (const float*)d_in[2];
  const int* c2v_s = (const int*)d_in[3];
  const int* c2v_t = (const int*)d_in[4];
  const int* a2v_s = (const int*)d_in[5];
  const int* a2v_t = (const int*)d_in[6];
  const float* ea_c2v = (const float*)d_in[7];
  const float* ea_a2v = (const float*)d_in[8];
  const float* gv_W1 = (const float*)d_in[9];
  const float* gv_b1 = (const float*)d_in[10];
  const float* gv_W2 = (const float*)d_in[11];
  const float* gv_b2 = (const float*)d_in[12];
  const float* hv_W1 = (const float*)d_in[13];
  const float* hv_b1 = (const float*)d_in[14];
  const float* hv_W2 = (const float*)d_in[15];
  const float* hv_b2 = (const float*)d_in[16];
  const float* fv_W1 = (const float*)d_in[17];
  const float* fv_b1 = (const float*)d_in[18];
  const float* fv_W2 = (const float*)d_in[19];
  const float* fv_b2 = (const float*)d_in[20];
  const float* ga_W1 = (const float*)d_in[21];
  const float* ga_b1 = (const float*)d_in[22];
  const float* ga_W2 = (const float*)d_in[23];
  const float* ga_b2 = (const float*)d_in[24];
  const float* fa_W1 = (const float*)d_in[25];
  const float* fa_b1 = (const float*)d_in[26];
  const float* fa_W2 = (const float*)d_in[27];
  const float* fa_b2 = (const float*)d_in[28];

  // ---- workspace layout: 28.1 MB total (proven envelope is ~39 MB) ----
  // Region A: CSR ints (615,004 ints = 2.46 MB)
  int* ip = (int*)d_ws;
  int* deg_g = ip;                  // 100000  -- memset region start
  int* deg_h = deg_g + N_V;         // 100000
  int* deg_a = deg_h + N_V;         // 5000
  int* ctr = deg_a + N_A;           // 4       -- memset region end
  int* off_g = ctr + 4;             // 100000
  int* off_h = off_g + N_V;         // 100000
  int* off_a = off_h + N_V;         // 5000
  int* head_g = off_a + N_A;        // 100000
  int* head_h = head_g + N_V;       // 100000
  int* head_a = head_h + N_V;       // 5000
  // Region B: 3.2M ints (12.8 MB), time-multiplexed:
  //   phase 1: perm_g(1.6M) + nid_g(1.6M)   [fill_g .. edge_g]
  //   phase 2: perm_h(1.0M) + nid_h(1.0M)   [fill_h .. edge_h]
  //   phase 3: fv (3.2M floats)             [node_fv .. aggr_a]
  int* B = head_a + N_A;
  int* perm_g = B;
  int* nid_g = B + E_C2V;
  int* perm_h = B;
  int* nid_h = B + E_A2V;
  float* fv = (float*)B;
  // Region C: 3.2M floats (12.8 MB), time-multiplexed:
  //   phase 1: hacc (N_V*32 f_v-hidden accumulator)  [edge_g .. node_fv]
  //   phase 2: perm_a(1.0M ints) + ma(160k floats)   [fill_a .. node_fa]
  float* C = (float*)(B + (size_t)2 * E_C2V);
  float* hacc = C;
  int* perm_a = (int*)C;
  float* ma = C + E_A2V;

  // zero degrees+ctr and hacc
  hipMemsetAsync(d_ws, 0, (size_t)(2 * N_V + N_A + 4) * sizeof(int), stream);
  hipMemsetAsync(C, 0, (size_t)N_V * EMB * sizeof(float), stream);

  // degrees + offsets (all sides; writes only region A)
  k_count<<<(E_C2V + 255) / 256, 256, 0, stream>>>(c2v_t, deg_g, E_C2V);
  k_count<<<(E_A2V + 255) / 256, 256, 0, stream>>>(a2v_t, deg_h, E_A2V);
  k_count<<<(E_A2V + 255) / 256, 256, 0, stream>>>(a2v_s, deg_a, E_A2V);
  k_alloc<<<(N_V + 255) / 256, 256, 0, stream>>>(deg_g, off_g, head_g, ctr + 0, N_V);
  k_alloc<<<(N_V + 255) / 256, 256, 0, stream>>>(deg_h, off_h, head_h, ctr + 1, N_V);
  k_alloc<<<(N_A + 255) / 256, 256, 0, stream>>>(deg_a, off_a, head_a, ctr + 2, N_A);

  // ---- g side: fill CSR into B, edge-parallel MLP+reduce into hacc
  k_fill2<<<(E_C2V + 255) / 256, 256, 0, stream>>>(c2v_t, head_g, perm_g, nid_g, E_C2V);
  k_edge_v<<<E_C2V / 256, 256, 0, stream>>>(
      E_C2V, perm_g, nid_g, c2v_s, x_v, x_c, ea_c2v,
      gv_W1, gv_b1, gv_W2, gv_b2, fv_W1 + (size_t)D_V * EMB, deg_g, hacc);
  // ---- h side: B reused (perm_g/nid_g dead)
  k_fill2<<<(E_A2V + 255) / 256, 256, 0, stream>>>(a2v_t, head_h, perm_h, nid_h, E_A2V);
  k_edge_v<<<(E_A2V + 255) / 256, 256, 0, stream>>>(
      E_A2V, perm_h, nid_h, a2v_s, x_v, x_a, ea_a2v,
      hv_W1, hv_b1, hv_W2, hv_b2, fv_W1 + (size_t)(D_V + EMB) * EMB, deg_h, hacc);
  // ---- f_v from hacc; fv lands in B (perm_h/nid_h dead)
  k_node_fv<<<(N_V + 255) / 256, 256, 0, stream>>>(
      x_v, hacc, fv_W1, fv_b1, fv_W2, fv_b2, fv);
  // ---- a side: perm_a lands in C (hacc dead)
  k_fill<<<(E_A2V + 255) / 256, 256, 0, stream>>>(a2v_s, head_a, perm_a, E_A2V);
  k_aggr_a<<<((size_t)N_A * 64 + 255) / 256, 256, 0, stream>>>(
      a2v_t, perm_a, off_a, deg_a, x_a, fv, ea_a2v,
      ga_W1, ga_b1, ga_W2, ga_b2, ma);
  k_node_fa<<<(N_A + 255) / 256, 256, 0, stream>>>(
      x_a, ma, fa_W1, fa_b1, fa_W2, fa_b2, (float*)d_out);
}

// Round 6
// 907.731 us; speedup vs baseline: 6.9796x; 1.1556x over previous
//
#include <hip/hip_runtime.h>

// Problem constants (from reference)
#define N_C 50000
#define N_V 100000
#define N_A 5000
#define E_C2V 1600000
#define E_A2V 1000000
#define D_V 13
#define D_C 14
#define D_A 14
#define EMB 32

// h[j] += v * Wrow[j]; Wrow wave-uniform -> scalar loads.
__device__ __forceinline__ void accrow(float* __restrict__ h, float v,
                                       const float* __restrict__ Wrow) {
#pragma unroll
  for (int j = 0; j < EMB; ++j) h[j] = fmaf(v, Wrow[j], h[j]);
}

// -------- merged degree histograms (one pass over the big edge range)
__global__ __launch_bounds__(256) void k_counts(
    const int* __restrict__ c2v_t, const int* __restrict__ a2v_t,
    const int* __restrict__ a2v_s, int* __restrict__ deg_g,
    int* __restrict__ deg_h, int* __restrict__ deg_a) {
  int e = blockIdx.x * blockDim.x + threadIdx.x;
  if (e < E_C2V) atomicAdd(&deg_g[c2v_t[e]], 1);
  if (e < E_A2V) {
    atomicAdd(&deg_h[a2v_t[e]], 1);
    atomicAdd(&deg_a[a2v_s[e]], 1);
  }
}

// -------- merged slot allocation: block-range selects side.
// off[i] = disjoint range of size deg[i] (wave scan + one atomic per wave).
#define NBV ((N_V + 255) / 256)  // 391
#define NBA ((N_A + 255) / 256)  // 20
__global__ __launch_bounds__(256) void k_allocs(
    const int* __restrict__ deg_g, int* __restrict__ off_g, int* __restrict__ head_g,
    const int* __restrict__ deg_h, int* __restrict__ off_h, int* __restrict__ head_h,
    const int* __restrict__ deg_a, int* __restrict__ off_a, int* __restrict__ head_a,
    int* __restrict__ ctr) {
  const int* deg;
  int* off;
  int* head;
  int* c;
  int i, n;
  if (blockIdx.x < NBV) {
    i = blockIdx.x * 256 + threadIdx.x;
    deg = deg_g; off = off_g; head = head_g; c = ctr + 0; n = N_V;
  } else if (blockIdx.x < 2 * NBV) {
    i = (blockIdx.x - NBV) * 256 + threadIdx.x;
    deg = deg_h; off = off_h; head = head_h; c = ctr + 1; n = N_V;
  } else {
    i = (blockIdx.x - 2 * NBV) * 256 + threadIdx.x;
    deg = deg_a; off = off_a; head = head_a; c = ctr + 2; n = N_A;
  }
  int lane = threadIdx.x & 63;
  int d = (i < n) ? deg[i] : 0;
  int v = d;  // inclusive wave scan
#pragma unroll
  for (int s = 1; s < 64; s <<= 1) {
    int t = __shfl_up(v, s, 64);
    if (lane >= s) v += t;
  }
  int total = __shfl(v, 63, 64);
  int base = 0;
  if (lane == 63) base = atomicAdd(c, total);
  base = __shfl(base, 63, 64);
  if (i < n) {
    int o = base + v - d;
    off[i] = o;
    head[i] = o;
  }
}

// -------- merged CSR fill for g side and a side (disjoint output regions)
__global__ __launch_bounds__(256) void k_fill_ga(
    const int* __restrict__ c2v_t, int* __restrict__ head_g,
    int* __restrict__ perm_g, int* __restrict__ nid_g,
    const int* __restrict__ a2v_s, int* __restrict__ head_a,
    int* __restrict__ perm_a, int* __restrict__ nid_a) {
  int e = blockIdx.x * blockDim.x + threadIdx.x;
  if (e < E_C2V) {
    int t = c2v_t[e];
    int pos = atomicAdd(&head_g[t], 1);
    perm_g[pos] = e;
    nid_g[pos] = t;
  }
  if (e < E_A2V) {
    int s = a2v_s[e];
    int pos = atomicAdd(&head_a[s], 1);
    perm_a[pos] = e;
    nid_a[pos] = s;
  }
}

// -------- CSR fill with node-id array (h side; runs after edge_g frees B)
__global__ __launch_bounds__(256) void k_fill2(const int* __restrict__ idx,
                                               int* __restrict__ head,
                                               int* __restrict__ perm,
                                               int* __restrict__ nidv, int n) {
  int e = blockIdx.x * blockDim.x + threadIdx.x;
  if (e < n) {
    int t = idx[e];
    int pos = atomicAdd(&head[t], 1);
    perm[pos] = e;
    nidv[pos] = t;
  }
}

// -------- edge-parallel v-side edge MLP (FIN=28) + per-wave segmented
// reduction + mean-scale + projection through the f_v W1 slice -> hacc.
// lane = CSR slot (edges grouped by dest v, groups contiguous).
__global__ __launch_bounds__(256) void k_edge_v(
    int E,
    const int* __restrict__ perm, const int* __restrict__ nid,
    const int* __restrict__ srcv,
    const float* __restrict__ x_t,   // variable-node feats (13)
    const float* __restrict__ x_s,   // source feats (14)
    const float* __restrict__ ea,    // 1 per edge
    const float* __restrict__ W1, const float* __restrict__ b1,
    const float* __restrict__ W2, const float* __restrict__ b2,
    const float* __restrict__ Wp,    // fW1 + (13 or 45)*32: projection slice
    const int* __restrict__ deg,
    float* __restrict__ hacc) {
  __shared__ float vals[4][64][33];  // +1 pad: scan reads conflict-free
  __shared__ int nidl[4][64];
  __shared__ float segx[4][32];
  int wv = threadIdx.x >> 6;
  int lane = threadIdx.x & 63;
  int slot = blockIdx.x * 256 + threadIdx.x;
  if ((slot & ~63) >= E) return;  // wave-uniform exit; no barriers used

  int e = perm[slot];
  int t = nid[slot];
  float eav = ea[e];
  int s = srcv[e];
  const float* xt = x_t + (size_t)t * D_V;

  float h[EMB];
#pragma unroll
  for (int j = 0; j < EMB; ++j) h[j] = b1[j];
#pragma unroll
  for (int i = 0; i < D_V; ++i) accrow(h, xt[i], W1 + i * EMB);
  // 14-dim source row: 56 B, 8 B aligned -> float2 x7
  const float2* xs2 = (const float2*)(x_s + (size_t)s * D_C);
#pragma unroll
  for (int i = 0; i < 7; ++i) {
    float2 w = xs2[i];
    accrow(h, w.x, W1 + (D_V + 2 * i) * EMB);
    accrow(h, w.y, W1 + (D_V + 2 * i + 1) * EMB);
  }
  accrow(h, eav, W1 + 27 * EMB);
#pragma unroll
  for (int j = 0; j < EMB; ++j) h[j] = fmaxf(h[j], 0.0f);
  // second layer, one output channel at a time (W2 index wave-uniform)
#pragma unroll
  for (int j = 0; j < EMB; ++j) {
    float o = b2[j];
#pragma unroll
    for (int k = 0; k < EMB; ++k) o = fmaf(h[k], W2[k * EMB + j], o);
    vals[wv][lane][j] = fmaxf(o, 0.0f);
  }
  nidl[wv][lane] = t;
  // wave-synchronous from here (DS ops in-order within a wave)
  if (lane < EMB) {
    int j = lane;
    float acc = 0.0f;
    for (int r = 0; r < 64; ++r) {
      acc += vals[wv][r][j];
      int cur = nidl[wv][r];
      bool flush = (r == 63) || (nidl[wv][r + 1] != cur);
      if (flush) {  // wave-uniform branch (same for all 32 lanes)
        float inv = 1.0f / fmaxf((float)deg[cur], 1.0f);
        segx[wv][j] = acc * inv;
        float out = 0.0f;
#pragma unroll
        for (int k = 0; k < EMB; ++k)
          out = fmaf(segx[wv][k], Wp[k * EMB + j], out);
        atomicAdd(&hacc[(size_t)cur * EMB + j], out);
        acc = 0.0f;
      }
    }
  }
}

// -------- edge-parallel a-side g_a MLP (FIN=47: [xa(14), fv(32), ea(1)])
// + segmented reduce + projection through fa_W1[14:46] -> hacc_a.
__global__ __launch_bounds__(256) void k_edge_a(
    const int* __restrict__ perm, const int* __restrict__ nid,
    const int* __restrict__ a2v_t,
    const float* __restrict__ xa_g, const float* __restrict__ fv,
    const float* __restrict__ ea,
    const float* __restrict__ W1, const float* __restrict__ b1,
    const float* __restrict__ W2, const float* __restrict__ b2,
    const float* __restrict__ Wp,   // fa_W1 + 14*32
    const int* __restrict__ deg,
    float* __restrict__ hacc_a) {
  __shared__ float vals[4][64][33];
  __shared__ int nidl[4][64];
  __shared__ float segx[4][32];
  int wv = threadIdx.x >> 6;
  int lane = threadIdx.x & 63;
  int slot = blockIdx.x * 256 + threadIdx.x;
  if ((slot & ~63) >= E_A2V) return;

  int e = perm[slot];
  int a = nid[slot];
  int t = a2v_t[e];
  float eav = ea[e];

  float h[EMB];
#pragma unroll
  for (int j = 0; j < EMB; ++j) h[j] = b1[j];
  const float2* ps2 = (const float2*)(xa_g + (size_t)a * D_A);
#pragma unroll
  for (int i = 0; i < 7; ++i) {
    float2 w = ps2[i];
    accrow(h, w.x, W1 + (2 * i) * EMB);
    accrow(h, w.y, W1 + (2 * i + 1) * EMB);
  }
  // fv row: 128 B, 16 B aligned -> float4 x8
  const float4* pf = (const float4*)(fv + (size_t)t * EMB);
#pragma unroll
  for (int q = 0; q < 8; ++q) {
    float4 f = pf[q];
    accrow(h, f.x, W1 + (D_A + 4 * q) * EMB);
    accrow(h, f.y, W1 + (D_A + 4 * q + 1) * EMB);
    accrow(h, f.z, W1 + (D_A + 4 * q + 2) * EMB);
    accrow(h, f.w, W1 + (D_A + 4 * q + 3) * EMB);
  }
  accrow(h, eav, W1 + 46 * EMB);
#pragma unroll
  for (int j = 0; j < EMB; ++j) h[j] = fmaxf(h[j], 0.0f);
#pragma unroll
  for (int j = 0; j < EMB; ++j) {
    float o = b2[j];
#pragma unroll
    for (int k = 0; k < EMB; ++k) o = fmaf(h[k], W2[k * EMB + j], o);
    vals[wv][lane][j] = fmaxf(o, 0.0f);
  }
  nidl[wv][lane] = a;
  if (lane < EMB) {
    int j = lane;
    float acc = 0.0f;
    for (int r = 0; r < 64; ++r) {
      acc += vals[wv][r][j];
      int cur = nidl[wv][r];
      bool flush = (r == 63) || (nidl[wv][r + 1] != cur);
      if (flush) {
        float inv = 1.0f / fmaxf((float)deg[cur], 1.0f);
        segx[wv][j] = acc * inv;
        float out = 0.0f;
#pragma unroll
        for (int k = 0; k < EMB; ++k)
          out = fmaf(segx[wv][k], Wp[k * EMB + j], out);
        atomicAdd(&hacc_a[(size_t)cur * EMB + j], out);
        acc = 0.0f;
      }
    }
  }
}

// -------- f_v node MLP on pre-accumulated hidden: thread per node.
__global__ __launch_bounds__(256) void k_node_fv(
    const float* __restrict__ xv_g, const float* __restrict__ hacc,
    const float* __restrict__ fW1, const float* __restrict__ fb1,
    const float* __restrict__ fW2, const float* __restrict__ fb2,
    float* __restrict__ fv_out) {
  int v = blockIdx.x * blockDim.x + threadIdx.x;
  if (v >= N_V) return;
  const float* hr = hacc + (size_t)v * EMB;
  float h[EMB];
#pragma unroll
  for (int j = 0; j < EMB; ++j) h[j] = fb1[j] + hr[j];
  const float* pv = xv_g + (size_t)v * D_V;
#pragma unroll
  for (int i = 0; i < D_V; ++i) accrow(h, pv[i], fW1 + i * EMB);
#pragma unroll
  for (int j = 0; j < EMB; ++j) h[j] = fmaxf(h[j], 0.0f);
  float* dst = fv_out + (size_t)v * EMB;
#pragma unroll
  for (int j = 0; j < EMB; ++j) {
    float o = fb2[j];
#pragma unroll
    for (int k = 0; k < EMB; ++k) o = fmaf(h[k], fW2[k * EMB + j], o);
    dst[j] = fmaxf(o, 0.0f);  // relu_out + reference's extra relu (idempotent)
  }
}

// -------- f_a node MLP on pre-accumulated hidden -> d_out
__global__ __launch_bounds__(256) void k_node_fa(
    const float* __restrict__ xa, const float* __restrict__ hacc_a,
    const float* __restrict__ W1, const float* __restrict__ b1,
    const float* __restrict__ W2, const float* __restrict__ b2,
    float* __restrict__ out) {
  int a = blockIdx.x * blockDim.x + threadIdx.x;
  if (a >= N_A) return;
  const float* hr = hacc_a + (size_t)a * EMB;
  float h[EMB];
#pragma unroll
  for (int j = 0; j < EMB; ++j) h[j] = b1[j] + hr[j];
  const float* pa = xa + (size_t)a * D_A;
#pragma unroll
  for (int i = 0; i < D_A; ++i) accrow(h, pa[i], W1 + i * EMB);
#pragma unroll
  for (int j = 0; j < EMB; ++j) h[j] = fmaxf(h[j], 0.0f);
  float* dst = out + (size_t)a * EMB;
#pragma unroll
  for (int j = 0; j < EMB; ++j) {
    float o = b2[j];
#pragma unroll
    for (int k = 0; k < EMB; ++k) o = fmaf(h[k], W2[k * EMB + j], o);
    dst[j] = fmaxf(o, 0.0f);
  }
}

extern "C" void kernel_launch(void* const* d_in, const int* in_sizes, int n_in,
                              void* d_out, int out_size, void* d_ws, size_t ws_size,
                              hipStream_t stream) {
  const float* x_c = (const float*)d_in[0];
  const float* x_v = (const float*)d_in[1];
  const float* x_a = (const float*)d_in[2];
  const int* c2v_s = (const int*)d_in[3];
  const int* c2v_t = (const int*)d_in[4];
  const int* a2v_s = (const int*)d_in[5];
  const int* a2v_t = (const int*)d_in[6];
  const float* ea_c2v = (const float*)d_in[7];
  const float* ea_a2v = (const float*)d_in[8];
  const float* gv_W1 = (const float*)d_in[9];
  const float* gv_b1 = (const float*)d_in[10];
  const float* gv_W2 = (const float*)d_in[11];
  const float* gv_b2 = (const float*)d_in[12];
  const float* hv_W1 = (const float*)d_in[13];
  const float* hv_b1 = (const float*)d_in[14];
  const float* hv_W2 = (const float*)d_in[15];
  const float* hv_b2 = (const float*)d_in[16];
  const float* fv_W1 = (const float*)d_in[17];
  const float* fv_b1 = (const float*)d_in[18];
  const float* fv_W2 = (const float*)d_in[19];
  const float* fv_b2 = (const float*)d_in[20];
  const float* ga_W1 = (const float*)d_in[21];
  const float* ga_b1 = (const float*)d_in[22];
  const float* ga_W2 = (const float*)d_in[23];
  const float* ga_b2 = (const float*)d_in[24];
  const float* fa_W1 = (const float*)d_in[25];
  const float* fa_b1 = (const float*)d_in[26];
  const float* fa_W2 = (const float*)d_in[27];
  const float* fa_b2 = (const float*)d_in[28];

  // ---- workspace layout: ~36.7 MB (proven envelope ~39 MB) ----
  // Region A: CSR ints (615,004 ints = 2.46 MB)
  int* ip = (int*)d_ws;
  int* deg_g = ip;                  // 100000  -- memset region start
  int* deg_h = deg_g + N_V;         // 100000
  int* deg_a = deg_h + N_V;         // 5000
  int* ctr = deg_a + N_A;           // 4       -- memset region end
  int* off_g = ctr + 4;             // 100000
  int* off_h = off_g + N_V;         // 100000
  int* off_a = off_h + N_V;         // 5000
  int* head_g = off_a + N_A;        // 100000
  int* head_h = head_g + N_V;       // 100000
  int* head_a = head_h + N_V;       // 5000
  // Region B: 3.2M ints (12.8 MB), time-multiplexed:
  //   phase 1: perm_g(1.6M) + nid_g(1.6M)   [fill_ga .. edge_g]
  //   phase 2: perm_h(1.0M) + nid_h(1.0M)   [fill_h .. edge_h]
  //   phase 3: fv (3.2M floats)             [node_fv .. edge_a]
  int* B = head_a + N_A;
  int* perm_g = B;
  int* nid_g = B + E_C2V;
  int* perm_h = B;
  int* nid_h = B + E_A2V;
  float* fv = (float*)B;
  // Region C: hacc (12.8 MB) + hacc_a (0.64 MB) — one contiguous memset
  float* hacc = (float*)(B + (size_t)2 * E_C2V);
  float* hacc_a = hacc + (size_t)N_V * EMB;
  // Region D: perm_a + nid_a (8 MB), lifetime fill_ga .. edge_a (no alias)
  int* perm_a = (int*)(hacc_a + (size_t)N_A * EMB);
  int* nid_a = perm_a + E_A2V;

  hipMemsetAsync(d_ws, 0, (size_t)(2 * N_V + N_A + 4) * sizeof(int), stream);
  hipMemsetAsync(hacc, 0, (size_t)(N_V + N_A) * EMB * sizeof(float), stream);

  // degrees (one pass) + offsets (one launch, block-range per side)
  k_counts<<<(E_C2V + 255) / 256, 256, 0, stream>>>(c2v_t, a2v_t, a2v_s,
                                                    deg_g, deg_h, deg_a);
  k_allocs<<<2 * NBV + NBA, 256, 0, stream>>>(deg_g, off_g, head_g,
                                              deg_h, off_h, head_h,
                                              deg_a, off_a, head_a, ctr);
  // CSR fill: g + a together (disjoint outputs), h later (aliases B)
  k_fill_ga<<<(E_C2V + 255) / 256, 256, 0, stream>>>(
      c2v_t, head_g, perm_g, nid_g, a2v_s, head_a, perm_a, nid_a);
  // g side edge MLP + reduce -> hacc
  k_edge_v<<<E_C2V / 256, 256, 0, stream>>>(
      E_C2V, perm_g, nid_g, c2v_s, x_v, x_c, ea_c2v,
      gv_W1, gv_b1, gv_W2, gv_b2, fv_W1 + (size_t)D_V * EMB, deg_g, hacc);
  // h side: B reused (perm_g/nid_g dead)
  k_fill2<<<(E_A2V + 255) / 256, 256, 0, stream>>>(a2v_t, head_h, perm_h, nid_h, E_A2V);
  k_edge_v<<<(E_A2V + 255) / 256, 256, 0, stream>>>(
      E_A2V, perm_h, nid_h, a2v_s, x_v, x_a, ea_a2v,
      hv_W1, hv_b1, hv_W2, hv_b2, fv_W1 + (size_t)(D_V + EMB) * EMB, deg_h, hacc);
  // f_v from hacc; fv lands in B (perm_h/nid_h dead)
  k_node_fv<<<(N_V + 255) / 256, 256, 0, stream>>>(
      x_v, hacc, fv_W1, fv_b1, fv_W2, fv_b2, fv);
  // a side edge MLP + reduce -> hacc_a
  k_edge_a<<<(E_A2V + 255) / 256, 256, 0, stream>>>(
      perm_a, nid_a, a2v_t, x_a, fv, ea_a2v,
      ga_W1, ga_b1, ga_W2, ga_b2, fa_W1 + (size_t)D_A * EMB, deg_a, hacc_a);
  // f_a -> out
  k_node_fa<<<(N_A + 255) / 256, 256, 0, stream>>>(
      x_a, hacc_a, fa_W1, fa_b1, fa_W2, fa_b2, (float*)d_out);
}